// Round 1
// baseline (133.501 us; speedup 1.0000x reference)
//
#include <hip/hip_runtime.h>

// Elementwise J2(x) for x in [0, 30] (fp32), Numerical-Recipes rational +
// asymptotic approximations, matching the JAX reference to ~1e-6.
//
// Math notes:
//  - x >= 0 for this problem (setup_inputs: uniform [0,30]); x==0 falls into
//    the |x|<1e-4 series branch, so sign(x)/fabs(x) handling is elided.
//  - Asymptotic phases: xx1 = xx0 - pi/2  =>  cos(xx1)=sin(xx0),
//    sin(xx1)=-cos(xx0). One __sincosf serves both J0 and J1.
//  - One v_rcp(ax) shared by z=8/ax, sqrt(2/(pi*ax)), and the 2/x recurrence.

__device__ __forceinline__ float bessj2_fast(float x) {
    float ax = x;                    // x >= 0
    float y  = x * x;

    // ---- small-|x| rational approximations (|x| < 8) ----
    float num0 = fmaf(y, fmaf(y, fmaf(y, fmaf(y, fmaf(y, -184.9052456f,
                  77392.33017f), -11214424.18f), 651619640.7f),
                  -13362590354.0f), 57568490574.0f);
    float den0 = fmaf(y, fmaf(y, fmaf(y, fmaf(y, (y + 267.8532712f),
                  59272.64853f), 9494680.718f), 1029532985.0f),
                  57568490411.0f);
    float j0_small = num0 * __builtin_amdgcn_rcpf(den0);

    float num1 = x * fmaf(y, fmaf(y, fmaf(y, fmaf(y, fmaf(y, -30.16036606f,
                  15704.48260f), -2972611.439f), 242396853.1f),
                  -7895059235.0f), 72362614232.0f);
    float den1 = fmaf(y, fmaf(y, fmaf(y, fmaf(y, (y + 376.9991397f),
                  99447.43394f), 18583304.74f), 2300535178.0f),
                  144725228442.0f);
    float j1_small = num1 * __builtin_amdgcn_rcpf(den1);

    // ---- large-|x| asymptotic approximations (|x| >= 8) ----
    float ax_s = fmaxf(ax, 1e-4f);           // safe for rcp; also x_safe for rec
    float rinv = __builtin_amdgcn_rcpf(ax_s);
    float z    = 8.0f * rinv;
    float yy   = z * z;
    float xx0  = ax_s - 0.785398164f;        // ax - pi/4

    float p10 = fmaf(yy, fmaf(yy, fmaf(yy, fmaf(yy, 0.2093887211e-6f,
                 -0.2073370639e-5f), 0.2734510407e-4f), -0.1098628627e-2f),
                 1.0f);
    float p20 = fmaf(yy, fmaf(yy, fmaf(yy, fmaf(yy, -0.934935152e-7f,
                 0.7621095161e-6f), -0.6911147651e-5f), 0.1430488765e-3f),
                 -0.1562499995e-1f);
    float p11 = fmaf(yy, fmaf(yy, fmaf(yy, fmaf(yy, -0.240337019e-6f,
                 0.2457520174e-5f), -0.3516396496e-4f), 0.183105e-2f),
                 1.0f);
    float p21 = fmaf(yy, fmaf(yy, fmaf(yy, fmaf(yy, 0.105787412e-6f,
                 -0.88228987e-6f), 0.8449199096e-5f), -0.2002690873e-3f),
                 0.04687499995f);

    float amp = __builtin_amdgcn_sqrtf(0.636619772f * rinv);  // sqrt(2/(pi*ax))
    float s0, c0;
    __sincosf(xx0, &s0, &c0);

    // J0_big = amp * (cos(xx0)*p10 - z*sin(xx0)*p20)
    float j0_big = amp * fmaf(c0, p10, -(z * s0 * p20));
    // J1_big = amp * (cos(xx1)*p11 - z*sin(xx1)*p21), xx1 = xx0 - pi/2
    //        = amp * (s0*p11 + z*c0*p21)     [sign(x)=1 here]
    float j1_big = amp * fmaf(s0, p11, z * c0 * p21);

    bool small = ax < 8.0f;
    float j0 = small ? j0_small : j0_big;
    float j1 = small ? j1_small : j1_big;

    // J2 = (2/x) J1 - J0   (rinv == 1/max(x,1e-4); discarded when ax<1e-4)
    float rec    = fmaf(2.0f * rinv, j1, -j0);
    float series = y * 0.125f;                // leading series x^2/8
    return (ax < 1e-4f) ? series : rec;
}

__global__ __launch_bounds__(256)
void j2_vec4_kernel(const float* __restrict__ in, float* __restrict__ out,
                    int n4) {
    const float4* in4  = reinterpret_cast<const float4*>(in);
    float4*       out4 = reinterpret_cast<float4*>(out);
    int idx    = blockIdx.x * blockDim.x + threadIdx.x;
    int stride = gridDim.x * blockDim.x;
    for (int i = idx; i < n4; i += stride) {
        float4 v = in4[i];
        float4 r;
        r.x = bessj2_fast(v.x);
        r.y = bessj2_fast(v.y);
        r.z = bessj2_fast(v.z);
        r.w = bessj2_fast(v.w);
        out4[i] = r;
    }
}

__global__ __launch_bounds__(256)
void j2_tail_kernel(const float* __restrict__ in, float* __restrict__ out,
                    int start, int n) {
    int i = start + blockIdx.x * blockDim.x + threadIdx.x;
    if (i < n) out[i] = bessj2_fast(in[i]);
}

extern "C" void kernel_launch(void* const* d_in, const int* in_sizes, int n_in,
                              void* d_out, int out_size, void* d_ws, size_t ws_size,
                              hipStream_t stream) {
    const float* in  = (const float*)d_in[0];
    float*       out = (float*)d_out;
    int n  = in_sizes[0];
    int n4 = n >> 2;                 // float4 chunks

    if (n4 > 0) {
        int blocks = (n4 + 255) / 256;
        if (blocks > 2048) blocks = 2048;   // grid-stride beyond this
        j2_vec4_kernel<<<blocks, 256, 0, stream>>>(in, out, n4);
    }
    int rem_start = n4 << 2;
    int rem = n - rem_start;
    if (rem > 0) {
        j2_tail_kernel<<<(rem + 255) / 256, 256, 0, stream>>>(in, out,
                                                              rem_start, n);
    }
}

// Round 2
// 105.272 us; speedup vs baseline: 1.2682x; 1.2682x over previous
//
#include <hip/hip_runtime.h>

// Elementwise J2(x), x in [0, 30], fp32. Direct-J2 approximations (instead of
// the reference's J0/J1 + recurrence) — we only need to match the reference
// to ~9.7e-3 ABSOLUTE, and both paths below are within ~1e-4 of true J2,
// while the reference is within ~1e-7. Compute per element:
//   x < 8 : Maclaurin series  J2 = u * sum_{k=0..12} (-1)^k u^k/(k!(k+2)!),
//           u = (x/2)^2.  13 fma + 2 mul. Truncation ~1e-5, roundoff ~7e-5.
//   x >= 8: Hankel asymptotic (mu=4n^2=16):
//           J2 = sqrt(2/(pi x)) [P2(yy) cos chi - Q2(yy) sin chi],
//           chi = x - 5pi/4, z = 8/x, yy = z^2,
//           P2 = 1 - 52.5 t^2 + 1299.375 t^4          (t = 1/(8x) = z/64)
//              = 1 + yy*(-1.28173828e-2 + yy*7.74472e-5)
//           Q2 = 15t + 157.5 t^3 - 16891.875 t^5
//              = z*(0.234375 + yy*(6.00815e-4 + yy*(-1.57318e-5)))
//           Checked: x=10 -> 0.254630 (true J2(10)=0.2546303).
// Branch select matches the reference's ax<8 split; the series limit u*0.5
// reproduces x^2/8 exactly, so no extra tiny-x branch is needed.

__device__ __forceinline__ float bessj2_fast(float x) {
    // ---- small path: power series in u = (x/2)^2 ----
    float u = 0.25f * x * x;
    float s;
    s = 2.39471e-20f;
    s = fmaf(s, u, -4.02324e-18f);
    s = fmaf(s, u,  5.75284e-16f);
    s = fmaf(s, u, -6.90369e-14f);
    s = fmaf(s, u,  6.83465e-12f);
    s = fmaf(s, u, -5.46772e-10f);
    s = fmaf(s, u,  3.44466e-08f);
    s = fmaf(s, u, -1.65344e-06f);
    s = fmaf(s, u,  5.78704e-05f);
    s = fmaf(s, u, -1.38889e-03f);
    s = fmaf(s, u,  2.08333e-02f);
    s = fmaf(s, u, -1.66667e-01f);
    s = fmaf(s, u,  0.5f);
    float j2_small = u * s;

    // ---- big path: Hankel asymptotic, n = 2 ----
    float xb   = fmaxf(x, 8.0f);               // keep rcp sane for small lanes
    float rinv = __builtin_amdgcn_rcpf(xb);
    float z    = 8.0f * rinv;
    float yy   = z * z;
    float amp  = __builtin_amdgcn_sqrtf(0.636619772f * rinv); // sqrt(2/(pi x))
    float chi  = xb - 3.92699082f;             // x - 5pi/4
    float sc, cc;
    __sincosf(chi, &sc, &cc);
    float p = fmaf(yy, fmaf(yy,  7.74472e-05f, -1.28173828e-02f), 1.0f);
    float q = z * fmaf(yy, fmaf(yy, -1.57318e-05f, 6.00815e-04f), 0.234375f);
    float j2_big = amp * fmaf(cc, p, -(sc * q));

    return (x < 8.0f) ? j2_small : j2_big;
}

__global__ __launch_bounds__(256)
void j2_vec4_kernel(const float* __restrict__ in, float* __restrict__ out,
                    int n4) {
    const float4* in4  = reinterpret_cast<const float4*>(in);
    float4*       out4 = reinterpret_cast<float4*>(out);
    int idx    = blockIdx.x * blockDim.x + threadIdx.x;
    int stride = gridDim.x * blockDim.x;
    for (int i = idx; i < n4; i += stride) {
        float4 v = in4[i];
        float4 r;
        r.x = bessj2_fast(v.x);
        r.y = bessj2_fast(v.y);
        r.z = bessj2_fast(v.z);
        r.w = bessj2_fast(v.w);
        out4[i] = r;
    }
}

__global__ __launch_bounds__(256)
void j2_tail_kernel(const float* __restrict__ in, float* __restrict__ out,
                    int start, int n) {
    int i = start + blockIdx.x * blockDim.x + threadIdx.x;
    if (i < n) out[i] = bessj2_fast(in[i]);
}

extern "C" void kernel_launch(void* const* d_in, const int* in_sizes, int n_in,
                              void* d_out, int out_size, void* d_ws, size_t ws_size,
                              hipStream_t stream) {
    const float* in  = (const float*)d_in[0];
    float*       out = (float*)d_out;
    int n  = in_sizes[0];
    int n4 = n >> 2;

    if (n4 > 0) {
        int blocks = (n4 + 255) / 256;
        if (blocks > 2048) blocks = 2048;   // 2048*256 threads = 8192 waves
        j2_vec4_kernel<<<blocks, 256, 0, stream>>>(in, out, n4);
    }
    int rem_start = n4 << 2;
    int rem = n - rem_start;
    if (rem > 0) {
        j2_tail_kernel<<<(rem + 255) / 256, 256, 0, stream>>>(in, out,
                                                              rem_start, n);
    }
}

// Round 3
// 100.802 us; speedup vs baseline: 1.3244x; 1.0443x over previous
//
#include <hip/hip_runtime.h>

// Elementwise J2(x), x in [0, 30], fp32. Direct-J2 approximations:
//   x < 8 : Maclaurin series  J2 = u * sum_{k=0..12} (-1)^k u^k/(k!(k+2)!),
//           u = (x/2)^2.  Truncation ~1e-5 at x=8.
//   x >= 8: Hankel asymptotic (mu=16):
//           J2 = sqrt(2/(pi x)) [P2(yy) cos chi - Q2(yy) sin chi],
//           chi = x - 5pi/4, z = 8/x, yy = z^2.
// Round-3 micro-opts vs round 2:
//   - one v_rsq replaces v_rcp + v_sqrt:  r = rsq(x); 1/x = r*r;
//     sqrt(2/(pi x)) = sqrt(2/pi) * r.   (saves 4 trans-pipe slots/elem)
//   - 2x manual unroll with both float4 loads issued before compute
//     (2 loads in flight per wave -> better latency hiding)
//   - non-temporal load/store hints (pure streaming, zero reuse)

typedef float vf4 __attribute__((ext_vector_type(4)));

__device__ __forceinline__ float bessj2_fast(float x) {
    // ---- small path: power series in u = (x/2)^2 ----
    float u = 0.25f * x * x;
    float s;
    s = 2.39471e-20f;
    s = fmaf(s, u, -4.02324e-18f);
    s = fmaf(s, u,  5.75284e-16f);
    s = fmaf(s, u, -6.90369e-14f);
    s = fmaf(s, u,  6.83465e-12f);
    s = fmaf(s, u, -5.46772e-10f);
    s = fmaf(s, u,  3.44466e-08f);
    s = fmaf(s, u, -1.65344e-06f);
    s = fmaf(s, u,  5.78704e-05f);
    s = fmaf(s, u, -1.38889e-03f);
    s = fmaf(s, u,  2.08333e-02f);
    s = fmaf(s, u, -1.66667e-01f);
    s = fmaf(s, u,  0.5f);
    float j2_small = u * s;

    // ---- big path: Hankel asymptotic, n = 2 ----
    float xb   = fmaxf(x, 8.0f);
    float r    = __builtin_amdgcn_rsqf(xb);      // 1/sqrt(x)
    float rinv = r * r;                          // 1/x
    float amp  = 0.797884561f * r;               // sqrt(2/(pi x))
    float z    = 8.0f * rinv;
    float yy   = z * z;
    float chi  = xb - 3.92699082f;               // x - 5pi/4
    float sc, cc;
    __sincosf(chi, &sc, &cc);
    float p = fmaf(yy, fmaf(yy,  7.74472e-05f, -1.28173828e-02f), 1.0f);
    float q = z * fmaf(yy, fmaf(yy, -1.57318e-05f, 6.00815e-04f), 0.234375f);
    float j2_big = amp * fmaf(cc, p, -(sc * q));

    return (x < 8.0f) ? j2_small : j2_big;
}

__device__ __forceinline__ vf4 j2_vec(vf4 v) {
    vf4 r;
    r.x = bessj2_fast(v.x);
    r.y = bessj2_fast(v.y);
    r.z = bessj2_fast(v.z);
    r.w = bessj2_fast(v.w);
    return r;
}

__global__ __launch_bounds__(256)
void j2_vec4_kernel(const float* __restrict__ in, float* __restrict__ out,
                    int n4) {
    const vf4* in4  = reinterpret_cast<const vf4*>(in);
    vf4*       out4 = reinterpret_cast<vf4*>(out);
    int idx    = blockIdx.x * blockDim.x + threadIdx.x;
    int stride = gridDim.x * blockDim.x;

    int i = idx;
    // 2x unrolled main loop: both loads issued before any compute.
    for (; i + stride < n4; i += 2 * stride) {
        vf4 a = __builtin_nontemporal_load(in4 + i);
        vf4 b = __builtin_nontemporal_load(in4 + i + stride);
        vf4 ra = j2_vec(a);
        vf4 rb = j2_vec(b);
        __builtin_nontemporal_store(ra, out4 + i);
        __builtin_nontemporal_store(rb, out4 + i + stride);
    }
    if (i < n4) {
        vf4 a = __builtin_nontemporal_load(in4 + i);
        __builtin_nontemporal_store(j2_vec(a), out4 + i);
    }
}

__global__ __launch_bounds__(256)
void j2_tail_kernel(const float* __restrict__ in, float* __restrict__ out,
                    int start, int n) {
    int i = start + blockIdx.x * blockDim.x + threadIdx.x;
    if (i < n) out[i] = bessj2_fast(in[i]);
}

extern "C" void kernel_launch(void* const* d_in, const int* in_sizes, int n_in,
                              void* d_out, int out_size, void* d_ws, size_t ws_size,
                              hipStream_t stream) {
    const float* in  = (const float*)d_in[0];
    float*       out = (float*)d_out;
    int n  = in_sizes[0];
    int n4 = n >> 2;

    if (n4 > 0) {
        int blocks = (n4 + 255) / 256;
        if (blocks > 2048) blocks = 2048;   // 2048*256 threads = 8192 waves
        j2_vec4_kernel<<<blocks, 256, 0, stream>>>(in, out, n4);
    }
    int rem_start = n4 << 2;
    int rem = n - rem_start;
    if (rem > 0) {
        j2_tail_kernel<<<(rem + 255) / 256, 256, 0, stream>>>(in, out,
                                                              rem_start, n);
    }
}